// Round 1
// baseline (60.494 us; speedup 1.0000x reference)
//
#include <hip/hip_runtime.h>

// QLinearGate analytic form:
//   The circuit is RY(x_q) on each qubit (product state, real amplitudes),
//   followed by only diagonal (RZ) and permutation (CNOT) gates. Phases never
//   interfere, so probabilities are a permuted product distribution and the
//   weights drop out. CNOT chain gives s_q = t_0^...^t_q, hence
//   <Z_q> = prod_{j<=q} cos(x_j).
// Pure element-wise kernel: one thread per batch row, float4 in / float4 out.

__global__ void QLinearGate_65481071408765_kernel(const float4* __restrict__ x,
                                                  float4* __restrict__ out,
                                                  int B) {
    int i = blockIdx.x * blockDim.x + threadIdx.x;
    if (i >= B) return;
    float4 v = x[i];
    float c0 = __cosf(v.x);
    float c1 = c0 * __cosf(v.y);
    float c2 = c1 * __cosf(v.z);
    float c3 = c2 * __cosf(v.w);
    out[i] = make_float4(c0, c1, c2, c3);
}

extern "C" void kernel_launch(void* const* d_in, const int* in_sizes, int n_in,
                              void* d_out, int out_size, void* d_ws, size_t ws_size,
                              hipStream_t stream) {
    const float4* x = (const float4*)d_in[0];   // [B,4] float32, row-major
    // d_in[1] (weight) is provably unused — RZ phases cancel in probabilities.
    float4* out = (float4*)d_out;               // [B,4] float32
    int B = in_sizes[0] / 4;                    // 524288
    int block = 256;
    int grid = (B + block - 1) / block;
    QLinearGate_65481071408765_kernel<<<grid, block, 0, stream>>>(x, out, B);
}